// Round 1
// baseline (373.109 us; speedup 1.0000x reference)
//
#include <hip/hip_runtime.h>

// GenSP: B=4, C=64, H=W=256, st=16 -> nH=nW=16, nS=256, P=65536
// out (B,nS,P) = 256MB dense, <=9 nonzeros per pixel column.
// M_COEF=0 -> grid channels zero; f2 (pixel norm) cancels in softmax.
//
// ws float layout:
//   num[65536] den[1024] cent0[65536] cent1[65536] c2[1024] aff[4*9*65536]
// Fast path (needs ~10.3MB ws): k_init -> k_stat -> k_cent -> k_aff -> k_write
//   k_write streams each (b,s) output plane CONTIGUOUSLY (256KB/block) at
//   fill-kernel write BW, gathering the sparse 48x48 strip from compact aff.
// Fallback (small ws): original k_out (scattered 1KB/plane stores).

#define PP 65536

typedef __attribute__((ext_vector_type(8))) short short8;
typedef __attribute__((ext_vector_type(4))) float f32x4;

__device__ __forceinline__ unsigned short f2bf(float f) {
  unsigned u = __float_as_uint(f);
  u += 0x7fff + ((u >> 16) & 1);   // round-nearest-even
  return (unsigned short)(u >> 16);
}

// ---- init: 16x16 block means -> cent0[(b*256+s)*64+c]; zero num/den ----
__global__ __launch_bounds__(256) void k_init(const float* __restrict__ x,
                                              float* __restrict__ cent0,
                                              float4* __restrict__ zero4) {
  __shared__ float blk[64];
  int t = threadIdx.x;
  int wg = blockIdx.x;
  int cg = wg & 15, bi = (wg >> 4) & 15, b = wg >> 8;
  int tid = wg * 256 + t;
  if (tid < 16640) zero4[tid] = make_float4(0.f, 0.f, 0.f, 0.f);  // num+den
  if (t < 64) blk[t] = 0.f;
  __syncthreads();
  int sub = t >> 6, j4 = t & 63;
#pragma unroll
  for (int q = 0; q < 4; q++) {
    int c = cg * 4 + q;
    const float4* xp4 =
        (const float4*)(x + ((long)(b * 64 + c) << 16) + ((bi * 16 + sub * 4) << 8)) + j4;
    float4 a = make_float4(0.f, 0.f, 0.f, 0.f);
#pragma unroll
    for (int r = 0; r < 4; r++) {
      float4 v = xp4[r * 64];
      a.x += v.x; a.y += v.y; a.z += v.z; a.w += v.w;
    }
    float ps = a.x + a.y + a.z + a.w;
    ps += __shfl_xor(ps, 1);
    ps += __shfl_xor(ps, 2);
    if ((j4 & 3) == 0) atomicAdd(&blk[(j4 >> 2) * 4 + q], ps);
  }
  __syncthreads();
  if (t < 64) {
    int sj = t >> 2, q = t & 3;
    cent0[(((b << 8) + bi * 16 + sj) << 6) + cg * 4 + q] = blk[t] * (1.f / 256.f);
  }
}

// ---- stat: wg = one 16x16 block; dot+softmax scalar, num via bf16 MFMA ----
__global__ __launch_bounds__(256) void k_stat(const float* __restrict__ x,
                                              const float* __restrict__ cent,
                                              float* __restrict__ num,
                                              float* __restrict__ den) {
  __shared__ __align__(16) unsigned short xbf[64 * 264];
  __shared__ __align__(16) unsigned short affbf[16 * 264];
  __shared__ float cent_s[9 * 64];
  __shared__ float c2p[72];
  __shared__ float c2_s[9];
  __shared__ float den_s[36];
  __shared__ int scand[9];

  int t = threadIdx.x;
  int wg = blockIdx.x;            // b*256 + bi*16 + bj
  int bj = wg & 15, bi = (wg >> 4) & 15, b = wg >> 8;

  if (t < 9) {
    int di = t / 3 - 1, dj = t % 3 - 1;
    int ci = bi + di, cj = bj + dj;
    int sc = min(max(ci, 0), 15) * 16 + min(max(cj, 0), 15);
    bool valid = ((unsigned)ci < 16u) && ((unsigned)cj < 16u);
    scand[t] = valid ? sc : (-1 - sc);
  }
  for (int o = t; o < 144; o += 256) {
    int k = o >> 4, f4 = o & 15;
    int di = k / 3 - 1, dj = k % 3 - 1;
    int sc = min(max(bi + di, 0), 15) * 16 + min(max(bj + dj, 0), 15);
    *(float4*)&cent_s[k * 64 + f4 * 4] =
        *(const float4*)(cent + (((b << 8) + sc) << 6) + f4 * 4);
  }
  __syncthreads();
  if (t < 72) {
    int k = t >> 3, pt = t & 7;
    float s = 0.f;
#pragma unroll
    for (int m = 0; m < 8; m++) { float v = cent_s[k * 64 + pt * 8 + m]; s += v * v; }
    c2p[t] = s;
  }
  __syncthreads();
  if (t < 9) {
    float s = 0.f;
#pragma unroll
    for (int m = 0; m < 8; m++) s += c2p[t * 8 + m];
    c2_s[t] = s;
  }
  __syncthreads();

  int vbits = 0;
#pragma unroll
  for (int k = 0; k < 9; k++) {
    int ci = bi + k / 3 - 1, cj = bj + k % 3 - 1;
    if ((unsigned)ci < 16u && (unsigned)cj < 16u) vbits |= 1 << k;
  }

  int r = t >> 4, col = t & 15;
  const float* base = x + ((long)(b * 64) << 16) + ((bi * 16 + r) << 8) + (bj * 16 + col);
  float acc[9];
#pragma unroll
  for (int k = 0; k < 9; k++) acc[k] = 0.f;
#pragma unroll 8
  for (int c = 0; c < 64; c++) {
    float xv = base[(long)c << 16];
    xbf[c * 264 + t] = f2bf(xv);
#pragma unroll
    for (int k = 0; k < 9; k++) acc[k] = fmaf(xv, cent_s[k * 64 + c], acc[k]);
  }
  float mx = -1e30f;
#pragma unroll
  for (int k = 0; k < 9; k++) {
    float l = 2.f * acc[k] - c2_s[k];
    acc[k] = ((vbits >> k) & 1) ? l : -1e30f;
    mx = fmaxf(mx, acc[k]);
  }
  float sum = 0.f;
#pragma unroll
  for (int k = 0; k < 9; k++) {
    acc[k] = __expf(acc[k] - mx);
    sum += acc[k];
  }
  float rs = 1.f / sum;
#pragma unroll
  for (int k = 0; k < 9; k++) {
    acc[k] *= rs;
    affbf[k * 264 + t] = f2bf(acc[k]);
  }

  int lane = t & 63, w = t >> 6;
#pragma unroll
  for (int k = 0; k < 9; k++) {
    float v = acc[k];
    v += __shfl_xor(v, 1);
    v += __shfl_xor(v, 2);
    v += __shfl_xor(v, 4);
    v += __shfl_xor(v, 8);
    v += __shfl_xor(v, 16);
    v += __shfl_xor(v, 32);
    if (lane == 0) den_s[w * 9 + k] = v;
  }
  __syncthreads();
  if (t < 9) {
    float d = den_s[t] + den_s[9 + t] + den_s[18 + t] + den_s[27 + t];
    int sc = scand[t]; sc = sc >= 0 ? sc : (-1 - sc);
    atomicAdd(&den[(b << 8) + sc], d);
  }

  // num GEMM: wave w owns c-tile [16w,16w+16); 8 K-steps of 16x16x32 bf16 MFMA
  int mrow = lane & 15;
  int quad = lane >> 4;
  f32x4 dacc = {0.f, 0.f, 0.f, 0.f};
#pragma unroll
  for (int ks = 0; ks < 8; ks++) {
    int p0 = ks * 32 + quad * 8;
    short8 a = *(const short8*)&xbf[(w * 16 + mrow) * 264 + p0];
    short8 bf = *(const short8*)&affbf[mrow * 264 + p0];
    dacc = __builtin_amdgcn_mfma_f32_16x16x32_bf16(a, bf, dacc, 0, 0, 0);
  }
  int kcol = lane & 15;
  if (kcol < 9) {
    int sc = scand[kcol]; sc = sc >= 0 ? sc : (-1 - sc);
    float* np = num + (((b << 8) + sc) << 6) + w * 16 + quad * 4;
    atomicAdd(&np[0], dacc[0]);
    atomicAdd(&np[1], dacc[1]);
    atomicAdd(&np[2], dacc[2]);
    atomicAdd(&np[3], dacc[3]);
  }
}

// ---- cent: cent1 = num/den, c2 = |cent1|^2. wave per (b,s) ----
__global__ __launch_bounds__(256) void k_cent(const float* __restrict__ num,
                                              const float* __restrict__ den,
                                              float* __restrict__ cent1,
                                              float* __restrict__ c2) {
  int t = threadIdx.x;
  int idx = blockIdx.x * 4 + (t >> 6);   // b*256 + s
  int c = t & 63;
  float d = den[idx] + 1e-16f;
  float v = num[(idx << 6) + c] / d;
  cent1[(idx << 6) + c] = v;
  float s2 = v * v;
  s2 += __shfl_xor(s2, 1);
  s2 += __shfl_xor(s2, 2);
  s2 += __shfl_xor(s2, 4);
  s2 += __shfl_xor(s2, 8);
  s2 += __shfl_xor(s2, 16);
  s2 += __shfl_xor(s2, 32);
  if (c == 0) c2[idx] = s2;
}

// ---- aff: final 9-way softmax per pixel, compact store aff[b][k][p] ----
__global__ __launch_bounds__(256) void k_aff(const float* __restrict__ x,
                                             const float* __restrict__ cent,
                                             const float* __restrict__ c2,
                                             float* __restrict__ aff) {
  __shared__ float cent_s[9 * 64];
  __shared__ float c2_s[9];

  int t = threadIdx.x;
  int wg = blockIdx.x;            // b*256 + bi*16 + bj
  int bj = wg & 15, bi = (wg >> 4) & 15, b = wg >> 8;

  for (int o = t; o < 144; o += 256) {
    int k = o >> 4, f4 = o & 15;
    int sc = min(max(bi + k / 3 - 1, 0), 15) * 16 + min(max(bj + k % 3 - 1, 0), 15);
    *(float4*)&cent_s[k * 64 + f4 * 4] =
        *(const float4*)(cent + (((b << 8) + sc) << 6) + f4 * 4);
  }
  if (t < 9) {
    int sc = min(max(bi + t / 3 - 1, 0), 15) * 16 + min(max(bj + t % 3 - 1, 0), 15);
    c2_s[t] = c2[(b << 8) + sc];
  }
  __syncthreads();

  int vbits = 0;
#pragma unroll
  for (int k = 0; k < 9; k++) {
    int ci = bi + k / 3 - 1, cj = bj + k % 3 - 1;
    if ((unsigned)ci < 16u && (unsigned)cj < 16u) vbits |= 1 << k;
  }

  int r = t >> 4, col = t & 15;
  const float* base = x + ((long)(b * 64) << 16) + ((bi * 16 + r) << 8) + (bj * 16 + col);
  float acc[9];
#pragma unroll
  for (int k = 0; k < 9; k++) acc[k] = 0.f;
#pragma unroll 8
  for (int c = 0; c < 64; c++) {
    float xv = base[(long)c << 16];
#pragma unroll
    for (int k = 0; k < 9; k++) acc[k] = fmaf(xv, cent_s[k * 64 + c], acc[k]);
  }
  float mx = -1e30f;
#pragma unroll
  for (int k = 0; k < 9; k++) {
    float l = 2.f * acc[k] - c2_s[k];
    acc[k] = ((vbits >> k) & 1) ? l : -1e30f;
    mx = fmaxf(mx, acc[k]);
  }
  float sum = 0.f;
#pragma unroll
  for (int k = 0; k < 9; k++) {
    acc[k] = __expf(acc[k] - mx);
    sum += acc[k];
  }
  float rs = 1.f / sum;
  int p = ((bi * 16 + r) << 8) + (bj * 16 + col);
#pragma unroll
  for (int k = 0; k < 9; k++)
    aff[(((long)(b * 9 + k)) << 16) + p] = acc[k] * rs;
}

// ---- write: one block per (b,s) plane; CONTIGUOUS 256KB nt stream ----
// Row index i is wave-uniform per store -> zero/nonzero branch is uniform.
// Nonzero strip (48 rows x 12 f32x4) gathers from compact aff (L2-hot).
__global__ __launch_bounds__(256) void k_write(const float* __restrict__ aff,
                                               f32x4* __restrict__ out4) {
  int t = threadIdx.x;
  int wg = blockIdx.x;            // b*256 + s
  int s = wg & 255, b = wg >> 8;
  int si = s >> 4, sj = s & 15;
  f32x4* op = out4 + ((long)wg << 14);
  const f32x4 zero = {0.f, 0.f, 0.f, 0.f};
#pragma unroll 4
  for (int m = 0; m < 64; m++) {
    int idx = m * 256 + t;
    int i = idx >> 6, j4 = idx & 63;
    int kr = si - (i >> 4) + 1;           // wave-uniform
    int kc = sj - (j4 >> 2) + 1;
    f32x4 v = zero;
    if ((unsigned)kr <= 2u && (unsigned)kc <= 2u) {
      int k = kr * 3 + kc;
      const f32x4* ap = (const f32x4*)(aff + (((long)(b * 9 + k)) << 16));
      v = ap[idx];
    }
    __builtin_nontemporal_store(v, &op[idx]);
  }
}

// ---- fallback out: finalize cents + affinity for one row + half s-planes ----
__global__ __launch_bounds__(256) void k_out(const float* __restrict__ x,
                                             const float* __restrict__ num,
                                             const float* __restrict__ den,
                                             f32x4* __restrict__ out4) {
  __shared__ float cent_s[48 * 68];
  __shared__ float den_s[48];
  __shared__ float c2p[384];
  __shared__ float c2_s[48];
  __shared__ float aff_t[9 * 260];

  int t = threadIdx.x;
  int wg = blockIdx.x;
  int h = wg & 1, i = (wg >> 1) & 255, b = wg >> 9;
  int bi = i >> 4;

  if (t < 48) {
    int ci = min(max(bi - 1 + (t >> 4), 0), 15);
    int cj = t & 15;
    den_s[t] = den[(b << 8) + ci * 16 + cj] + 1e-16f;
  }
  __syncthreads();
  for (int o = t; o < 768; o += 256) {
    int lr = o >> 4, f4i = o & 15;
    int ci = min(max(bi - 1 + (lr >> 4), 0), 15);
    int cj = lr & 15;
    float4 v = *(const float4*)(num + (((b << 8) + ci * 16 + cj) << 6) + f4i * 4);
    float inv = 1.f / den_s[lr];
    v.x *= inv; v.y *= inv; v.z *= inv; v.w *= inv;
    *(float4*)&cent_s[lr * 68 + f4i * 4] = v;
  }
  __syncthreads();
  for (int o = t; o < 384; o += 256) {
    int lr = o >> 3, pt = o & 7;
    float s = 0.f;
#pragma unroll
    for (int m = 0; m < 8; m++) { float v = cent_s[lr * 68 + pt * 8 + m]; s += v * v; }
    c2p[o] = s;
  }
  __syncthreads();
  if (t < 48) {
    float s = 0.f;
#pragma unroll
    for (int m = 0; m < 8; m++) s += c2p[t * 8 + m];
    c2_s[t] = s;
  }
  __syncthreads();

  int j = t, bj = j >> 4;
  int cidx[9];
  float c2k[9];
  int vbits = 0;
#pragma unroll
  for (int k = 0; k < 9; k++) {
    int di = k / 3 - 1, dj = k % 3 - 1;
    int ciu = bi + di, cju = bj + dj;
    if ((unsigned)ciu < 16u && (unsigned)cju < 16u) vbits |= 1 << k;
    int lidx = (di + 1) * 16 + min(max(cju, 0), 15);
    cidx[k] = lidx * 68;
    c2k[k] = c2_s[lidx];
  }
  const float* base = x + ((long)(b * 64) << 16) + (i << 8) + j;
  float acc[9];
#pragma unroll
  for (int k = 0; k < 9; k++) acc[k] = 0.f;
#pragma unroll 8
  for (int c = 0; c < 64; c++) {
    float xv = base[(long)c << 16];
#pragma unroll
    for (int k = 0; k < 9; k++) acc[k] = fmaf(xv, cent_s[cidx[k] + c], acc[k]);
  }
  float mx = -1e30f;
#pragma unroll
  for (int k = 0; k < 9; k++) {
    float l = 2.f * acc[k] - c2k[k];
    acc[k] = ((vbits >> k) & 1) ? l : -1e30f;
    mx = fmaxf(mx, acc[k]);
  }
  float sum = 0.f;
#pragma unroll
  for (int k = 0; k < 9; k++) {
    acc[k] = __expf(acc[k] - mx);
    sum += acc[k];
  }
  float rs = 1.f / sum;
#pragma unroll
  for (int k = 0; k < 9; k++) aff_t[k * 260 + j] = acc[k] * rs;
  __syncthreads();

  f32x4* obase = out4 + ((long)(b << 8) << 14) + (i << 6) + (t & 63);
  int j4 = t & 63;
  int w = t >> 6;
  int s0 = h << 7;
#pragma unroll 4
  for (int m = 0; m < 32; m++) {
    int s = s0 | (m << 2) | w;
    f32x4 v = {0.f, 0.f, 0.f, 0.f};
    int di = (s >> 4) - bi;
    if ((unsigned)(di + 1) <= 2u) {
      int dj = (s & 15) - (j4 >> 2);
      if ((unsigned)(dj + 1) <= 2u) {
        int k = (di + 1) * 3 + dj + 1;
        v = *(const f32x4*)&aff_t[k * 260 + (j4 << 2)];
      }
    }
    __builtin_nontemporal_store(v, &obase[(long)s << 14]);
  }
}

extern "C" void kernel_launch(void* const* d_in, const int* in_sizes, int n_in,
                              void* d_out, int out_size, void* d_ws, size_t ws_size,
                              hipStream_t stream) {
  const float* x = (const float*)d_in[0];
  float* out = (float*)d_out;
  float* ws = (float*)d_ws;

  float* num   = ws;
  float* den   = ws + 65536;
  float* cent0 = ws + 66560;
  float* cent1 = ws + 132096;
  float* c2    = ws + 197632;
  float* aff   = ws + 198656;
  const size_t need_floats = 198656 + (size_t)4 * 9 * 65536;  // 2,557,952

  k_init<<<1024, 256, 0, stream>>>(x, cent0, (float4*)ws);
  k_stat<<<1024, 256, 0, stream>>>(x, cent0, num, den);

  if (ws_size >= need_floats * sizeof(float)) {
    k_cent<<<256, 256, 0, stream>>>(num, den, cent1, c2);
    k_aff<<<1024, 256, 0, stream>>>(x, cent1, c2, aff);
    k_write<<<1024, 256, 0, stream>>>(aff, (f32x4*)out);
  } else {
    k_out<<<2048, 256, 0, stream>>>(x, num, den, (f32x4*)out);
  }
}